// Round 18
// baseline (110.504 us; speedup 1.0000x reference)
//
#include <hip/hip_runtime.h>

#define N_SERIES 1024
#define N_TIME 600
#define INPUT_SIZE 168
#define OUTPUT_SIZE 24
#define N_S 4
#define SEAS 24
#define N_WINDOWS (N_TIME - INPUT_SIZE - OUTPUT_SIZE + 1) /* 409 */
#define SEAS_LEN (N_TIME + SEAS)                          /* 624 */

#define INS_ELEMS (N_WINDOWS * N_SERIES * (INPUT_SIZE + N_S)) /* 72,036,352 */
#define OUTS_ELEMS (N_WINDOWS * N_SERIES * OUTPUT_SIZE)       /* 10,051,584 */
#define LEV_ELEMS (N_SERIES * N_TIME)

#define NQ_OUTS (OUTS_ELEMS / 4) /* 2,512,896 */

#define SCAN_BLOCKS 16
#define SCAN_T 64
#define COPY_BLOCKS 2032

/* ins4: 2048 blocks = 256 series-groups x 8 window-segments; 256 thr */
#define INS4_BLOCKS 2048
#define WSEG 52 /* last segment gets 409 - 7*52 = 45 */

typedef float f4 __attribute__((ext_vector_type(4)));

// ---------------------------------------------------------------------------
// Kernel 1 (R13 scan verbatim): blocks [0,16): register-only scan, direct f4
// row stores. blocks [16,...): outsample copy — now CACHED stores (the single
// variable this round: L2 write-combining vs NT bypass).
// ---------------------------------------------------------------------------
__global__ __launch_bounds__(SCAN_T) void scan_copy_kernel(
    const float* __restrict__ y, const float* __restrict__ embeds,
    const int* __restrict__ idxs, float* __restrict__ levels,
    float* __restrict__ seas1, f4* __restrict__ out_outs)
{
    if (blockIdx.x < SCAN_BLOCKS) {
        const int lane = threadIdx.x;
        const int s = blockIdx.x * SCAN_T + lane;
        const int row = idxs[s];
        const float* e = embeds + row * (2 + SEAS);

        const float lev_sms = 1.0f / (1.0f + __expf(-e[0]));
        const float seas_sms = 1.0f / (1.0f + __expf(-e[1]));
        const float one_m_lev = 1.0f - lev_sms;
        const float one_m_seas = 1.0f - seas_sms;

        const float* yrow = y + s * N_TIME;
        const f4* yv4 = (const f4*)yrow;
        float* lrow = levels + s * N_TIME;
        float* srow = seas1 + s * SEAS_LEN;

        f4 cur[6], nxt[6];
#pragma unroll
        for (int i = 0; i < 6; ++i) cur[i] = yv4[i];

        float sb[SEAS];
#pragma unroll
        for (int j = 0; j < SEAS; ++j) sb[j] = __expf(e[2 + j]);

#pragma unroll
        for (int k = 0; k < 6; ++k) {
            f4 v = {sb[4 * k], sb[4 * k + 1], sb[4 * k + 2], sb[4 * k + 3]};
            *(f4*)(srow + 4 * k) = v;
        }

        float lev = __fdividef(cur[0].x, sb[0]);

        f4 fl[6], fs[6];
        fl[0].x = lev;
        fs[0].x = sb[0];
        {
#pragma unroll
            for (int i = 0; i < 6; ++i) nxt[i] = yv4[6 + i];
#pragma unroll
            for (int j = 1; j < 24; ++j) {
                float yt = cur[j >> 2][j & 3];
                float st = sb[j];
                float q1 = __fdividef(yt, st);
                float newlev = lev_sms * q1 + one_m_lev * lev;
                float news =
                    seas_sms * __fdividef(yt, newlev) + one_m_seas * st;
                lev = newlev;
                sb[j] = news;
                fl[j >> 2][j & 3] = newlev;
                fs[j >> 2][j & 3] = news;
            }
#pragma unroll
            for (int k = 0; k < 6; ++k) {
                *(f4*)(lrow + 4 * k) = fl[k];
                *(f4*)(srow + SEAS + 4 * k) = fs[k];
            }
#pragma unroll
            for (int i = 0; i < 6; ++i) cur[i] = nxt[i];
        }

#pragma unroll 1
        for (int c = 1; c < 25; ++c) {
            const int t0 = 24 * c;
            if (c < 24) {
                const f4* p = (const f4*)(yrow + 24 * (c + 1));
#pragma unroll
                for (int i = 0; i < 6; ++i) nxt[i] = p[i];
            }
#pragma unroll
            for (int j = 0; j < 24; ++j) {
                float yt = cur[j >> 2][j & 3];
                float st = sb[j];
                float q1 = __fdividef(yt, st);
                float newlev = lev_sms * q1 + one_m_lev * lev;
                float news =
                    seas_sms * __fdividef(yt, newlev) + one_m_seas * st;
                lev = newlev;
                sb[j] = news;
                fl[j >> 2][j & 3] = newlev;
                fs[j >> 2][j & 3] = news;
            }
#pragma unroll
            for (int k = 0; k < 6; ++k) {
                *(f4*)(lrow + t0 + 4 * k) = fl[k];
                *(f4*)(srow + SEAS + t0 + 4 * k) = fs[k];
            }
#pragma unroll
            for (int i = 0; i < 6; ++i) cur[i] = nxt[i];
        }
    } else {
        int idx = (blockIdx.x - SCAN_BLOCKS) * SCAN_T + threadIdx.x;
        const int stride = (gridDim.x - SCAN_BLOCKS) * SCAN_T;
        for (; idx < NQ_OUTS; idx += stride) {
            int rowq = idx / 6;
            int j4 = idx - rowq * 6;
            int w = rowq >> 10;
            int s = rowq & 1023;
            const float* yp = y + s * N_TIME + w + INPUT_SIZE + j4 * 4;
            f4 v = {yp[0], yp[1], yp[2], yp[3]};
            out_outs[idx] = v; // cached store
        }
    }
}

// ---------------------------------------------------------------------------
// Kernel 2 (ins4, R17 verbatim except CACHED stores): block (g, seg) owns
// series [4g, 4g+4) x a 52-window segment. LDS-staged log tables (mod-4
// layout, conflict-free), ~17 requests/KB, 8 blocks/CU. The store policy is
// the only change: plain stores let L2 absorb + write-combine the 288 MB
// stream (the memset fill proves cached streaming = ~7 TB/s).
// ---------------------------------------------------------------------------
__global__ __launch_bounds__(256) void ins4_kernel(
    const float* __restrict__ y, const float* __restrict__ levels,
    const float* __restrict__ seas1, const float* __restrict__ s_matrix,
    f4* __restrict__ out_ins)
{
    __shared__ __align__(16) float tq[4][4][57];  // [sl][t'&3][t'>>2]
    __shared__ __align__(16) float llv[4][224];   // [sl][t']
    __shared__ f4 sml[4];

    const int tid = threadIdx.x;
    const int g = blockIdx.x >> 3;
    const int seg = blockIdx.x & 7;
    const int s0 = g * 4;
    const int w0 = seg * WSEG;
    const int nw = (seg == 7) ? (N_WINDOWS - 7 * WSEG) : WSEG; /* 45 or 52 */

    // ---- staging: 224 f4-tasks (4 series x 56 f4 of the t-slice)
    for (int i = tid; i < 224; i += 256) {
        int sl = i / 56;
        int c = i - sl * 56;
        int s = s0 + sl;
        int t = w0 + 4 * c; // w0 % 4 == 0 -> f4-aligned
        f4 yv = *(const f4*)(y + s * N_TIME + t);
        f4 sv = *(const f4*)(seas1 + s * SEAS_LEN + t);
        f4 lv = *(const f4*)(levels + s * N_TIME + t);
        tq[sl][0][c] = __logf(__fdividef(yv.x, sv.x));
        tq[sl][1][c] = __logf(__fdividef(yv.y, sv.y));
        tq[sl][2][c] = __logf(__fdividef(yv.z, sv.z));
        tq[sl][3][c] = __logf(__fdividef(yv.w, sv.w));
        f4 lg = {__logf(lv.x), __logf(lv.y), __logf(lv.z), __logf(lv.w)};
        *(f4*)(&llv[sl][4 * c]) = lg;
    }
    if (tid < 4) sml[tid] = *((const f4*)s_matrix + (s0 + tid));
    __syncthreads();

    // ---- main loop: ql -> (w', sl, e4); t' = w' + 4*e4 + j
    const int ntask = nw * 172;
    for (int ql = tid; ql < ntask; ql += 256) {
        int wp = ql / 172;
        int slot = ql - 172 * wp;
        int sl = slot / 43;
        int e4 = slot - 43 * sl;
        f4 v;
        if (e4 == 42) {
            v = sml[sl];
        } else {
            float l = llv[sl][wp + 167];
            int a0 = wp, a1 = wp + 1, a2 = wp + 2, a3 = wp + 3;
            v.x = tq[sl][a0 & 3][(a0 >> 2) + e4] - l;
            v.y = tq[sl][a1 & 3][(a1 >> 2) + e4] - l;
            v.z = tq[sl][a2 & 3][(a2 >> 2) + e4] - l;
            v.w = tq[sl][a3 & 3][(a3 >> 2) + e4] - l;
        }
        out_ins[(w0 + wp) * (N_SERIES * 43) + (s0 + sl) * 43 + e4] = v; // cached
    }
}

extern "C" void kernel_launch(void* const* d_in, const int* in_sizes, int n_in,
                              void* d_out, int out_size, void* d_ws, size_t ws_size,
                              hipStream_t stream) {
    const float* y      = (const float*)d_in[0];
    const float* sm     = (const float*)d_in[1];
    const float* embeds = (const float*)d_in[2];
    const int*   idxs   = (const int*)d_in[3];

    float* out      = (float*)d_out;
    float* out_ins  = out;
    float* out_outs = out + INS_ELEMS;
    float* out_lev  = out + INS_ELEMS + OUTS_ELEMS;
    float* out_seas = out_lev + LEV_ELEMS;

    (void)d_ws; (void)ws_size;

    scan_copy_kernel<<<SCAN_BLOCKS + COPY_BLOCKS, SCAN_T, 0, stream>>>(
        y, embeds, idxs, out_lev, out_seas, (f4*)out_outs);
    ins4_kernel<<<INS4_BLOCKS, 256, 0, stream>>>(
        y, out_lev, out_seas, sm, (f4*)out_ins);
}

// Round 19
// 103.409 us; speedup vs baseline: 1.0686x; 1.0686x over previous
//
#include <hip/hip_runtime.h>

#define N_SERIES 1024
#define N_TIME 600
#define INPUT_SIZE 168
#define OUTPUT_SIZE 24
#define N_S 4
#define SEAS 24
#define N_WINDOWS (N_TIME - INPUT_SIZE - OUTPUT_SIZE + 1) /* 409 */
#define SEAS_LEN (N_TIME + SEAS)                          /* 624 */

#define INS_ELEMS (N_WINDOWS * N_SERIES * (INPUT_SIZE + N_S)) /* 72,036,352 */
#define OUTS_ELEMS (N_WINDOWS * N_SERIES * OUTPUT_SIZE)       /* 10,051,584 */
#define LEV_ELEMS (N_SERIES * N_TIME)
#define SEAS_ELEMS (N_SERIES * SEAS_LEN)

#define NQ_OUTS (OUTS_ELEMS / 4)              /* 2,512,896 */
#define NQ_INS43 (N_WINDOWS * N_SERIES * 43)  /* 18,009,088 */
#define INS_SLICE (NQ_INS43 / 8)              /* 2,251,136 (43|SLICE, 64|SLICE) */

#define SCAN_BLOCKS 16
#define SCAN_T 64
#define COPY_BLOCKS 2032
#define INS_BLOCKS 2048
#define WS_NEEDED (2u * LEV_ELEMS * sizeof(float)) /* tbl + llv = 4.9 MB */

typedef float f4 __attribute__((ext_vector_type(4)));

// ---------------------------------------------------------------------------
// Kernel 1 (fused):
//   blocks [0,16): exponential-smoothing scan — ZERO LDS, ZERO fences.
//     Each lane owns one series end-to-end: 24-step chunks computed into
//     6+6 f4 register accumulators, stored directly to the lane's own row
//     (16B-aligned: byte offs 96c ≡ 0 mod 16). Stores are per-lane scattered
//     across rows — that's TA throughput only (~8 µs for 4.9 MB), vs the old
//     LDS-transpose path which exposed ~120cy ds_read latency 24x/chunk with
//     a single wave (no TLP to hide it). Cached stores (L2 merges the 16B
//     partial lines; NT would force HBM RMW — R11 lesson).
//   blocks [16,...): outsample window copy, dense wave-aligned, nontemporal.
// ---------------------------------------------------------------------------
__global__ __launch_bounds__(SCAN_T) void scan_copy_kernel(
    const float* __restrict__ y, const float* __restrict__ embeds,
    const int* __restrict__ idxs, float* __restrict__ levels,
    float* __restrict__ seas1, f4* __restrict__ out_outs)
{
    if (blockIdx.x < SCAN_BLOCKS) {
        const int lane = threadIdx.x;
        const int s = blockIdx.x * SCAN_T + lane;
        const int row = idxs[s];
        const float* e = embeds + row * (2 + SEAS);

        const float lev_sms = 1.0f / (1.0f + __expf(-e[0]));
        const float seas_sms = 1.0f / (1.0f + __expf(-e[1]));
        const float one_m_lev = 1.0f - lev_sms;
        const float one_m_seas = 1.0f - seas_sms;

        const float* yrow = y + s * N_TIME;
        const f4* yv4 = (const f4*)yrow; // row stride 2400B keeps 16B align
        float* lrow = levels + s * N_TIME;   // byte base s*2400, 16B-aligned
        float* srow = seas1 + s * SEAS_LEN;  // byte base s*2496, 16B-aligned

        f4 cur[6], nxt[6];
#pragma unroll
        for (int i = 0; i < 6; ++i) cur[i] = yv4[i];

        float sb[SEAS];
#pragma unroll
        for (int j = 0; j < SEAS; ++j) sb[j] = __expf(e[2 + j]);

        // init seasonality cols 0..23 straight from registers
#pragma unroll
        for (int k = 0; k < 6; ++k) {
            f4 v = {sb[4 * k], sb[4 * k + 1], sb[4 * k + 2], sb[4 * k + 3]};
            *(f4*)(srow + 4 * k) = v;
        }

        float lev = __fdividef(cur[0].x, sb[0]);

        f4 fl[6], fs[6];
        // ---- chunk 0: t = 1..23 (ring index = t); slot t=0 carries the
        //      specials: levels[0] = level0, seas col 24 = init sb[0].
        fl[0].x = lev;
        fs[0].x = sb[0];
        {
#pragma unroll
            for (int i = 0; i < 6; ++i) nxt[i] = yv4[6 + i];
#pragma unroll
            for (int j = 1; j < 24; ++j) {
                float yt = cur[j >> 2][j & 3];
                float st = sb[j];
                float q1 = __fdividef(yt, st);
                float newlev = lev_sms * q1 + one_m_lev * lev;
                float news =
                    seas_sms * __fdividef(yt, newlev) + one_m_seas * st;
                lev = newlev;
                sb[j] = news;
                fl[j >> 2][j & 3] = newlev;
                fs[j >> 2][j & 3] = news;
            }
#pragma unroll
            for (int k = 0; k < 6; ++k) {
                *(f4*)(lrow + 4 * k) = fl[k];            // levels t=0..23
                *(f4*)(srow + SEAS + 4 * k) = fs[k];     // seas cols 24..47
            }
#pragma unroll
            for (int i = 0; i < 6; ++i) cur[i] = nxt[i];
        }

        // ---- chunks c = 1..24: t = 24c + j, ring index = j ----
#pragma unroll 1
        for (int c = 1; c < 25; ++c) {
            const int t0 = 24 * c;
            if (c < 24) {
                const f4* p = (const f4*)(yrow + 24 * (c + 1));
#pragma unroll
                for (int i = 0; i < 6; ++i) nxt[i] = p[i];
            }
#pragma unroll
            for (int j = 0; j < 24; ++j) {
                float yt = cur[j >> 2][j & 3];
                float st = sb[j];
                float q1 = __fdividef(yt, st);
                float newlev = lev_sms * q1 + one_m_lev * lev;
                float news =
                    seas_sms * __fdividef(yt, newlev) + one_m_seas * st;
                lev = newlev;
                sb[j] = news;
                fl[j >> 2][j & 3] = newlev;
                fs[j >> 2][j & 3] = news;
            }
#pragma unroll
            for (int k = 0; k < 6; ++k) {
                *(f4*)(lrow + t0 + 4 * k) = fl[k];
                *(f4*)(srow + SEAS + t0 + 4 * k) = fs[k];
            }
#pragma unroll
            for (int i = 0; i < 6; ++i) cur[i] = nxt[i];
        }
    } else {
        // copy role: outsample windows — dense wave-aligned, nontemporal
        int idx = (blockIdx.x - SCAN_BLOCKS) * SCAN_T + threadIdx.x;
        const int stride = (gridDim.x - SCAN_BLOCKS) * SCAN_T;
        for (; idx < NQ_OUTS; idx += stride) {
            int rowq = idx / 6;
            int j4 = idx - rowq * 6;
            int w = rowq >> 10;
            int s = rowq & 1023;
            const float* yp = y + s * N_TIME + w + INPUT_SIZE + j4 * 4;
            f4 v = {yp[0], yp[1], yp[2], yp[3]};
            __builtin_nontemporal_store(v, &out_outs[idx]);
        }
    }
}

// ---------------------------------------------------------------------------
// Kernel 2: full-GPU parallel log pass:
//   tbl[s][t] = log(y/seas1), llv[s][t] = log(levels).
// ---------------------------------------------------------------------------
__global__ __launch_bounds__(256) void logpass_kernel(
    const float* __restrict__ y, const float* __restrict__ levels,
    const float* __restrict__ seas1, float* __restrict__ tbl,
    float* __restrict__ llv)
{
    int i = blockIdx.x * 256 + threadIdx.x; // f4 index over [0, 153600)
    int sr = i / 150;
    int c = i - sr * 150;
    f4 a = *((const f4*)(y + sr * N_TIME) + c);
    f4 se = *((const f4*)(seas1 + sr * SEAS_LEN) + c); // 2496B rows, aligned
    f4 l = *((const f4*)(levels + sr * N_TIME) + c);
    f4 ta, tl;
    ta.x = __logf(__fdividef(a.x, se.x));
    ta.y = __logf(__fdividef(a.y, se.y));
    ta.z = __logf(__fdividef(a.z, se.z));
    ta.w = __logf(__fdividef(a.w, se.w));
    tl.x = __logf(l.x);
    tl.y = __logf(l.y);
    tl.z = __logf(l.z);
    tl.w = __logf(l.w);
    ((f4*)tbl)[i] = ta;
    ((f4*)llv)[i] = tl;
}

// ---------------------------------------------------------------------------
// Kernel 3 (best known): insample rows incl. static column.
// XCD-clustered 1/8 q-slices; NT stores (wave-aligned full lines);
// incremental rowq/e4 (65536 = 43*1524 + 4).
// ---------------------------------------------------------------------------
__global__ __launch_bounds__(256) void ins_kernel(
    const float* __restrict__ tbl, const float* __restrict__ llv,
    const float* __restrict__ s_matrix, f4* __restrict__ out_ins)
{
    const f4* sm4 = (const f4*)s_matrix;
    const int xcd = blockIdx.x & 7;
    const int lb = blockIdx.x >> 3; // 0..255
    const int qend = (xcd + 1) * INS_SLICE;
    const int stride = (INS_BLOCKS / 8) * 256; /* 65536 */
    int q = xcd * INS_SLICE + lb * 256 + (int)threadIdx.x;
    int rowq = q / 43;
    int e4 = q - rowq * 43;
    for (; q < qend; q += stride) {
        int w = rowq >> 10;
        int s = rowq & 1023;
        f4 v;
        if (e4 == 42) {
            v = sm4[s];
        } else {
            int t = w + e4 * 4;
            const float* tp = tbl + s * N_TIME + t;
            float lv = llv[s * N_TIME + w + INPUT_SIZE - 1];
            v.x = tp[0] - lv;
            v.y = tp[1] - lv;
            v.z = tp[2] - lv;
            v.w = tp[3] - lv;
        }
        __builtin_nontemporal_store(v, &out_ins[q]);
        rowq += 1524;
        e4 += 4;
        if (e4 >= 43) {
            e4 -= 43;
            rowq += 1;
        }
    }
}

// Fallback (ws too small): compute logs on the fly, same XCD clustering.
__global__ __launch_bounds__(256) void ins_kernel_fb(
    const float* __restrict__ y, const float* __restrict__ levels,
    const float* __restrict__ seas1, const float* __restrict__ s_matrix,
    f4* __restrict__ out_ins)
{
    const f4* sm4 = (const f4*)s_matrix;
    const int xcd = blockIdx.x & 7;
    const int lb = blockIdx.x >> 3;
    const int qend = (xcd + 1) * INS_SLICE;
    const int stride = (INS_BLOCKS / 8) * 256;
    for (int q = xcd * INS_SLICE + lb * 256 + (int)threadIdx.x; q < qend;
         q += stride) {
        int rowq = q / 43;
        int e4 = q - rowq * 43;
        int w = rowq >> 10;
        int s = rowq & 1023;
        f4 v;
        if (e4 == 42) {
            v = sm4[s];
        } else {
            int t = w + e4 * 4;
            float lev = levels[s * N_TIME + w + INPUT_SIZE - 1];
            const float* yp = y + s * N_TIME + t;
            const float* sp = seas1 + s * SEAS_LEN + t;
            float vv[4];
#pragma unroll
            for (int j = 0; j < 4; ++j)
                vv[j] = __logf(__fdividef(yp[j], lev * sp[j]));
            v.x = vv[0]; v.y = vv[1]; v.z = vv[2]; v.w = vv[3];
        }
        __builtin_nontemporal_store(v, &out_ins[q]);
    }
}

extern "C" void kernel_launch(void* const* d_in, const int* in_sizes, int n_in,
                              void* d_out, int out_size, void* d_ws, size_t ws_size,
                              hipStream_t stream) {
    const float* y      = (const float*)d_in[0];
    const float* sm     = (const float*)d_in[1];
    const float* embeds = (const float*)d_in[2];
    const int*   idxs   = (const int*)d_in[3];

    float* out      = (float*)d_out;
    float* out_ins  = out;
    float* out_outs = out + INS_ELEMS;
    float* out_lev  = out + INS_ELEMS + OUTS_ELEMS;
    float* out_seas = out_lev + LEV_ELEMS;

    float* tbl = (float*)d_ws;
    float* llv = tbl + LEV_ELEMS;
    const int have_ws = (ws_size >= (size_t)WS_NEEDED) ? 1 : 0;

    scan_copy_kernel<<<SCAN_BLOCKS + COPY_BLOCKS, SCAN_T, 0, stream>>>(
        y, embeds, idxs, out_lev, out_seas, (f4*)out_outs);
    if (have_ws) {
        logpass_kernel<<<LEV_ELEMS / 4 / 256, 256, 0, stream>>>(
            y, out_lev, out_seas, tbl, llv);
        ins_kernel<<<INS_BLOCKS, 256, 0, stream>>>(tbl, llv, sm,
                                                   (f4*)out_ins);
    } else {
        ins_kernel_fb<<<INS_BLOCKS, 256, 0, stream>>>(y, out_lev, out_seas,
                                                      sm, (f4*)out_ins);
    }
}